// Round 9
// baseline (1145.669 us; speedup 1.0000x reference)
//
#include <hip/hip_runtime.h>
#include <hip/hip_bf16.h>

#define NN 100000
#define NNP 100096   // padded rows: multiple of 256
#define NE 1600000
#define FIN 500
#define HID 128

typedef __attribute__((ext_vector_type(8))) short short8;   // 8 bf16 = 4 VGPRs (MFMA A/B frag)
typedef __attribute__((ext_vector_type(4))) float f32x4;    // MFMA C/D frag

__device__ __forceinline__ float bf2f(unsigned short u) {
    return __uint_as_float(((unsigned int)u) << 16);
}
__device__ __forceinline__ unsigned short f2bf(float f) {
    __hip_bfloat16 h = __float2bfloat16(f);
    return *(unsigned short*)&h;
}
__device__ __forceinline__ float lo16(unsigned int v) { return __uint_as_float(v << 16); }
__device__ __forceinline__ float hi16(unsigned int v) { return __uint_as_float(v & 0xffff0000u); }

// direct global->LDS 16B: no result VGPRs, so all staging loads stay in flight.
__device__ __forceinline__ void gload_lds16(const void* g, void* l) {
    __builtin_amdgcn_global_load_lds(
        (const __attribute__((address_space(1))) unsigned int*)g,
        (__attribute__((address_space(3))) unsigned int*)l, 16, 0, 0);
}

// ---------- template-named kernel (serves as cnt zeroing) ----------

__global__ __launch_bounds__(256) void GCNLarge_20761871909627_kernel(int* __restrict__ buf, int n) {
    int i = blockIdx.x * 256 + threadIdx.x;
    if (i < n) buf[i] = 0;
}

// ---------- runtime layout detection (wave-parallel) ----------

__global__ void detect_kernel(const int* __restrict__ ei, const unsigned int* __restrict__ xw,
                              int* __restrict__ flags) {
    int lane = threadIdx.x & 63;
    int any = 0;
    for (int k = lane; k < 128; k += 64) any |= ei[2 * k + 1];
    int hits = 0;
    for (int k = lane; k < 256; k += 64) {
        unsigned e = (xw[k] >> 7) & 0xFF;
        hits += (e >= 100 && e <= 140) ? 1 : 0;
    }
#pragma unroll
    for (int o = 32; o > 0; o >>= 1) {
        any |= __shfl_down(any, o);
        hits += __shfl_down(hits, o);
    }
    if (lane == 0) {
        flags[0] = (any == 0) ? 1 : 0;
        flags[1] = (hits >= 128) ? 1 : 0;
    }
}

__device__ __forceinline__ int edge_src(const int* ei, int e, int m) {
    return m ? ei[2 * (size_t)e] : ei[e];
}
__device__ __forceinline__ int edge_dst(const int* ei, int e, int m) {
    return m ? ei[2 * (size_t)NE + 2 * (size_t)e] : ei[(size_t)NE + e];
}

// ---------- degree / CSR build ----------
// count's atomic return IS the edge's rank within its dst -> store rank[e]; place is
// atomic-free: csr[off[d]+rank[e]] = s. (round-6 fix, confirmed -73us)

__global__ __launch_bounds__(256) void count_kernel(const int* __restrict__ ei,
                                                    const int* __restrict__ flags,
                                                    int* __restrict__ cnt,
                                                    int* __restrict__ rank) {
    int m = flags[0];
    int base = blockIdx.x * 1024 + threadIdx.x;
#pragma unroll
    for (int i = 0; i < 4; i++) {
        int e = base + i * 256;
        if (e < NE) {
            int d = edge_dst(ei, e, m);
            if ((unsigned)d < NN) rank[e] = atomicAdd(&cnt[d], 1);
        }
    }
}

__global__ __launch_bounds__(256) void dis_kernel(const int* __restrict__ cnt,
                                                  float* __restrict__ dis) {
    int i = blockIdx.x * 256 + threadIdx.x;
    if (i < NNP) {
        int c = (i < NN) ? cnt[i] : 0;
        if (c < 0) c = 0;
        dis[i] = rsqrtf((float)(c + 1));
    }
}

__global__ __launch_bounds__(1024) void scan1_kernel(const int* __restrict__ cnt,
                                                     int* __restrict__ off,
                                                     int* __restrict__ bsum) {
    __shared__ int s[1024];
    int i = blockIdx.x * 1024 + threadIdx.x;
    int v = (i < NN) ? cnt[i] : 0;
    s[threadIdx.x] = v;
    __syncthreads();
    for (int d = 1; d < 1024; d <<= 1) {
        int tv = (threadIdx.x >= d) ? s[threadIdx.x - d] : 0;
        __syncthreads();
        s[threadIdx.x] += tv;
        __syncthreads();
    }
    if (i < NN) off[i] = s[threadIdx.x] - v;
    if (threadIdx.x == 1023) bsum[blockIdx.x] = s[1023];
}

__global__ void scan2_kernel(int* __restrict__ bsum, int nb) {
    if (threadIdx.x == 0 && blockIdx.x == 0) {
        int acc = 0;
        for (int b = 0; b < nb; b++) { int v = bsum[b]; bsum[b] = acc; acc += v; }
    }
}

__global__ __launch_bounds__(1024) void scan3_kernel(int* __restrict__ off,
                                                     const int* __restrict__ bsum) {
    int i = blockIdx.x * 1024 + threadIdx.x;
    if (i < NN) off[i] = off[i] + bsum[blockIdx.x];
    if (i == 0) off[NN] = NE;
}

// atomic-free placement: slot = off[d] + rank[e] (unique by construction)
__global__ __launch_bounds__(256) void place_kernel(const int* __restrict__ ei,
                                                    const int* __restrict__ flags,
                                                    const int* __restrict__ off,
                                                    const int* __restrict__ rank,
                                                    int* __restrict__ csr) {
    int m = flags[0];
    int base = blockIdx.x * 1024 + threadIdx.x;
#pragma unroll
    for (int i = 0; i < 4; i++) {
        int e = base + i * 256;
        if (e < NE) {
            int s = edge_src(ei, e, m);
            int d = edge_dst(ei, e, m);
            if ((unsigned)s < NN && (unsigned)d < NN) {
                int slot = off[d] + rank[e];
                if ((unsigned)slot < NE) csr[slot] = s;
            }
        }
    }
}

// ---------- W -> W^T (bf16) in global: Wt[n][k] = W[k][n], zero-padded to Kpad ----------

__global__ __launch_bounds__(256) void wt_kernel(const void* __restrict__ W,
                                                 const int* __restrict__ flags,
                                                 unsigned short* __restrict__ Wt,
                                                 int K, int Kpad, int total) {
    int idx = blockIdx.x * 256 + threadIdx.x;
    if (idx >= total) return;
    int n = idx / Kpad, k = idx - n * Kpad;
    unsigned short v = 0;
    if (k < K) {
        if (flags[1]) v = ((const unsigned short*)W)[(size_t)k * HID + n];
        else          v = f2bf(((const float*)W)[(size_t)k * HID + n]);
    }
    Wt[idx] = v;
}

// ---------- layers 2-4: barrier-free register GEMM ----------

__global__ __launch_bounds__(256) void gemmWr_kernel(const unsigned short* __restrict__ A,
                                                     const unsigned short* __restrict__ Wt,
                                                     const float* __restrict__ dis,
                                                     unsigned short* __restrict__ out) {
    int tid = threadIdx.x;
    int w = tid >> 6, lane = tid & 63;
    int m = lane & 15, quad = lane >> 4;
    int mbase = (w >> 1) * 32, nbase = (w & 1) * 64;
    short8 b[4][4];
#pragma unroll
    for (int nt = 0; nt < 4; nt++)
#pragma unroll
        for (int kq = 0; kq < 4; kq++)
            b[nt][kq] = *(const short8*)(Wt + (size_t)(nbase + nt * 16 + m) * HID + kq * 32 + quad * 8);
    int t0 = blockIdx.x * 4;
    short8 aP[4][2], aQ[4][2];
    auto loadA = [&](int t, short8 a[4][2]) {
        const unsigned short* p0 = A + (size_t)(t * 64 + mbase + m) * HID + quad * 8;
        const unsigned short* p1 = p0 + (size_t)16 * HID;
#pragma unroll
        for (int kq = 0; kq < 4; kq++) {
            a[kq][0] = *(const short8*)(p0 + kq * 32);
            a[kq][1] = *(const short8*)(p1 + kq * 32);
        }
    };
    loadA(t0, aP);
#pragma unroll
    for (int tt = 0; tt < 4; tt++) {
        if (tt < 3) loadA(t0 + tt + 1, (tt & 1) ? aP : aQ);
        short8 (*ac)[2] = (tt & 1) ? aQ : aP;
        f32x4 acc[2][4] = {};
#pragma unroll
        for (int kq = 0; kq < 4; kq++)
#pragma unroll
            for (int nt = 0; nt < 4; nt++) {
                acc[0][nt] = __builtin_amdgcn_mfma_f32_16x16x32_bf16(ac[kq][0], b[nt][kq], acc[0][nt], 0, 0, 0);
                acc[1][nt] = __builtin_amdgcn_mfma_f32_16x16x32_bf16(ac[kq][1], b[nt][kq], acc[1][nt], 0, 0, 0);
            }
        int r0 = (t0 + tt) * 64;
#pragma unroll
        for (int mt = 0; mt < 2; mt++) {
            int rb = r0 + mbase + mt * 16 + quad * 4;
#pragma unroll
            for (int reg = 0; reg < 4; reg++) {
                float d = dis[rb + reg];
#pragma unroll
                for (int nt = 0; nt < 4; nt++)
                    out[(size_t)(rb + reg) * HID + nbase + nt * 16 + m] = f2bf(acc[mt][nt][reg] * d);
            }
        }
    }
}

// ---------- layer 1: x [NN,500] @ Wt1[128][512], global_load_lds staging ----------

__global__ __launch_bounds__(256) void gemm1g_kernel(const void* __restrict__ Av,
                                                     const unsigned short* __restrict__ Wt1,
                                                     const float* __restrict__ dis,
                                                     const int* __restrict__ flags,
                                                     unsigned short* __restrict__ out) {
    __shared__ __align__(16) char lds[65536];
    float* AsF         = (float*)lds;                      // fp32 path: A slice [64][128] f32, 32KB
    unsigned short* Bs = (unsigned short*)(lds + 32768);   // B slice [128][128] bf16, 32KB
    unsigned short* As = (unsigned short*)lds;             // bf16 path: A slice [64][128] bf16, 16KB
    int tid = threadIdx.x;
    int bf = flags[1];
    int w = tid >> 6, lane = tid & 63;
    int m = lane & 15, quad = lane >> 4;
    int mbase = (w >> 1) * 32, nbase = (w & 1) * 64;
    int r0 = blockIdx.x * 64;
    f32x4 acc[2][4] = {};
    if (!bf) {
        // ---------------- fp32-x path (bench path) ----------------
#pragma unroll 1
        for (int kc = 0; kc < 4; kc++) {
            // B: 2048 16B slots; slot s=(n,cs) holds global chunk cs^(n&7)
#pragma unroll
            for (int i = 0; i < 8; i++) {
                int base = (i * 4 + w) * 64;
                int s = base + lane;
                int n = s >> 4, cs = s & 15;
                int csrc = cs ^ (n & 7);
                gload_lds16((const char*)Wt1 + (size_t)n * 1024 + kc * 256 + csrc * 16,
                            (char*)Bs + (size_t)base * 16);
            }
            // A: 2048 16B slots (fp32); slot s=(r,cs) holds global chunk cs^(r&7)
#pragma unroll
            for (int i = 0; i < 8; i++) {
                int base = (i * 4 + w) * 64;
                int s = base + lane;
                int r = s >> 5, cs = s & 31;
                int csrc = cs ^ (r & 7);
                int grow = r0 + r; int gr = (grow < NN) ? grow : NN - 1;
                int rb = kc * 512 + csrc * 16;          // byte offset within 2000B row
                size_t gb = (size_t)gr * 2000 + rb;
                if (rb + 16 > 2000) gb = 0;             // clamp OOB tail (x B-pad-zero)
                gload_lds16((const char*)Av + gb, (char*)lds + (size_t)base * 16);
            }
            __syncthreads();   // one vmcnt drain for all 16 loads/thread
#pragma unroll
            for (int kq = 0; kq < 4; kq++) {
                int g = kq * 4 + quad;
                int ra = mbase + m, rb2 = mbase + 16 + m;
                int fa = ra & 7, fb = rb2 & 7;
                float4 x0 = *(const float4*)(AsF + ra  * 128 + (((2 * g)     ^ fa) * 4));
                float4 x1 = *(const float4*)(AsF + ra  * 128 + (((2 * g + 1) ^ fa) * 4));
                float4 y0 = *(const float4*)(AsF + rb2 * 128 + (((2 * g)     ^ fb) * 4));
                float4 y1 = *(const float4*)(AsF + rb2 * 128 + (((2 * g + 1) ^ fb) * 4));
                short8 a0 = short8{(short)f2bf(x0.x), (short)f2bf(x0.y), (short)f2bf(x0.z), (short)f2bf(x0.w),
                                   (short)f2bf(x1.x), (short)f2bf(x1.y), (short)f2bf(x1.z), (short)f2bf(x1.w)};
                short8 a1 = short8{(short)f2bf(y0.x), (short)f2bf(y0.y), (short)f2bf(y0.z), (short)f2bf(y0.w),
                                   (short)f2bf(y1.x), (short)f2bf(y1.y), (short)f2bf(y1.z), (short)f2bf(y1.w)};
#pragma unroll
                for (int nt = 0; nt < 4; nt++) {
                    int n = nbase + nt * 16 + m;
                    short8 b = *(const short8*)(Bs + (size_t)n * 128 + ((g ^ (n & 7)) * 8));
                    acc[0][nt] = __builtin_amdgcn_mfma_f32_16x16x32_bf16(a0, b, acc[0][nt], 0, 0, 0);
                    acc[1][nt] = __builtin_amdgcn_mfma_f32_16x16x32_bf16(a1, b, acc[1][nt], 0, 0, 0);
                }
            }
            __syncthreads();   // protect slices from next kc staging
        }
    } else {
        // ---------------- bf16-x path (round-2 verified reg staging) ----------------
        int srow = tid >> 5;
        int scol = (tid & 31) * 4;
        int schunk = scol >> 3;
        int shalf = (scol >> 2) & 1;
#pragma unroll 1
        for (int kc = 0; kc < 4; kc++) {
#pragma unroll
            for (int it = 0; it < 8; it++) {
                int chunk = it * 256 + tid;
                int n = chunk >> 4, c = chunk & 15;
                int sc = c ^ (n & 15);
                *(short8*)(&Bs[n * 128 + c * 8]) =
                    *(const short8*)(Wt1 + (size_t)n * 512 + kc * 128 + sc * 8);
            }
#pragma unroll
            for (int i = 0; i < 8; i++) {
                int row = i * 8 + srow;
                int grow = r0 + row;
                int gr = (grow < NN) ? grow : NN - 1;
                int gcol = kc * 128 + scol;
                ushort4 pk = make_ushort4(0, 0, 0, 0);
                if (gcol + 4 <= FIN)
                    pk = *(const ushort4*)((const unsigned short*)Av + (size_t)gr * FIN + gcol);
                int pos = schunk ^ (row & 15);
                *(ushort4*)(&As[row * 128 + pos * 8 + shalf * 4]) = pk;
            }
            __syncthreads();
#pragma unroll
            for (int kq = 0; kq < 4; kq++) {
                int g = kq * 4 + quad;
                int ar0 = mbase + m;
                int ar1 = mbase + 16 + m;
                short8 a0 = *(const short8*)(&As[ar0 * 128 + ((g ^ m) * 8)]);
                short8 a1 = *(const short8*)(&As[ar1 * 128 + ((g ^ m) * 8)]);
#pragma unroll
                for (int nt = 0; nt < 4; nt++) {
                    int n = nbase + nt * 16 + m;
                    short8 b = *(const short8*)(&Bs[n * 128 + ((g ^ (n & 15)) * 8)]);
                    acc[0][nt] = __builtin_amdgcn_mfma_f32_16x16x32_bf16(a0, b, acc[0][nt], 0, 0, 0);
                    acc[1][nt] = __builtin_amdgcn_mfma_f32_16x16x32_bf16(a1, b, acc[1][nt], 0, 0, 0);
                }
            }
            __syncthreads();
        }
    }
#pragma unroll
    for (int mt = 0; mt < 2; mt++) {
        int rb = r0 + mbase + mt * 16 + quad * 4;
#pragma unroll
        for (int reg = 0; reg < 4; reg++) {
            int row = rb + reg;
            if (row < NN) {
                float d = dis[row];
#pragma unroll
                for (int nt = 0; nt < 4; nt++)
                    out[(size_t)row * HID + nbase + nt * 16 + m] = f2bf(acc[mt][nt][reg] * d);
            }
        }
    }
}

// ---------- aggregation over bf16 features, f32 accumulate ----------
// Round-8: aggb x5 is the dominant block (~450us est from budget). Gathers are
// L3-resident (25.6MB) -> latency-bound on ~500cy L3 hits. Old 8/4/1 unroll ladder
// paid E[ceil(deg/8)+tails] ~2.3 serialized latency batches per node; new single
// PREDICATED 16-edge batch (wave-uniform guards; masked edge -> idx=node, v=0)
// pays E[ceil(deg/16)] ~1.5, and deg<=16 nodes (53% at Poisson(16)) finish the
// gather phase in ONE latency. Indexing is fully unrolled (rule #20 safe).

__global__ __launch_bounds__(256) void aggb_kernel(const unsigned short* __restrict__ tin,
                                                   const int* __restrict__ off,
                                                   const int* __restrict__ csr,
                                                   const float* __restrict__ dis,
                                                   const void* __restrict__ bias,
                                                   const int* __restrict__ flags,
                                                   unsigned short* __restrict__ hout,
                                                   int relu, int scale_src) {
    int node = blockIdx.x * 4 + (threadIdx.x >> 6);   // one wave per node
    int lane = threadIdx.x & 63;                      // 2 features per lane (1 dword)
    float di = dis[node];
    unsigned int sv = *(const unsigned int*)(tin + (size_t)node * HID + lane * 2);
    float acc0 = scale_src ? di * lo16(sv) : lo16(sv);
    float acc1 = scale_src ? di * hi16(sv) : hi16(sv);
    int e0 = off[node], e1 = off[node + 1];
    if (e0 < 0) e0 = 0;
    if (e1 > NE) e1 = NE;
    int e = e0;
    if (!scale_src) {
        while (e < e1) {
            int rem = e1 - e;                          // wave-uniform
            int idx[16];
            unsigned int v[16];
#pragma unroll
            for (int j = 0; j < 16; j++) idx[j] = (j < rem) ? csr[e + j] : node;
#pragma unroll
            for (int j = 0; j < 16; j++)
                v[j] = (j < rem) ? *(const unsigned int*)(tin + (size_t)idx[j] * HID + lane * 2) : 0u;
#pragma unroll
            for (int j = 0; j < 16; j++) { acc0 += lo16(v[j]); acc1 += hi16(v[j]); }
            e += 16;
        }
    } else {
        while (e < e1) {
            int rem = e1 - e;                          // wave-uniform
            int idx[16];
            unsigned int v[16];
#pragma unroll
            for (int j = 0; j < 16; j++) idx[j] = (j < rem) ? csr[e + j] : node;
#pragma unroll
            for (int j = 0; j < 16; j++)
                v[j] = (j < rem) ? *(const unsigned int*)(tin + (size_t)idx[j] * HID + lane * 2) : 0u;
#pragma unroll
            for (int j = 0; j < 16; j++) {
                float mm = dis[idx[j]];                // masked j: dis[node] * 0 = 0
                acc0 += mm * lo16(v[j]);
                acc1 += mm * hi16(v[j]);
            }
            e += 16;
        }
    }
    float o0 = di * acc0, o1 = di * acc1;
    if (bias) {
        if (flags[1]) { o0 += bf2f(((const unsigned short*)bias)[lane * 2]);
                        o1 += bf2f(((const unsigned short*)bias)[lane * 2 + 1]); }
        else          { o0 += ((const float*)bias)[lane * 2];
                        o1 += ((const float*)bias)[lane * 2 + 1]; }
    }
    if (relu) { o0 = fmaxf(o0, 0.f); o1 = fmaxf(o1, 0.f); }
    unsigned int pk = ((unsigned int)f2bf(o1) << 16) | (unsigned int)f2bf(o0);
    *(unsigned int*)(hout + (size_t)node * HID + lane * 2) = pk;
}

// ---------- layer 5: bf16 [NN,128] @ W5 [128,3] + b5 -> out (dtype per flags[1]) ----------

__global__ __launch_bounds__(256) void gemm5_kernel(const unsigned short* __restrict__ A,
                                                    const void* __restrict__ W5v,
                                                    const void* __restrict__ b5v,
                                                    const int* __restrict__ flags,
                                                    void* __restrict__ outv) {
    __shared__ float Ws[384];
    __shared__ float bs[3];
    int tid = threadIdx.x;
    int bf = flags[1];
    for (int idx = tid; idx < 384; idx += 256)
        Ws[idx] = bf ? bf2f(((const unsigned short*)W5v)[idx]) : ((const float*)W5v)[idx];
    if (tid < 3)
        bs[tid] = bf ? bf2f(((const unsigned short*)b5v)[tid]) : ((const float*)b5v)[tid];
    __syncthreads();
    int lane = tid & 63;
    int row = blockIdx.x * 4 + (tid >> 6);
    float a0 = bf2f(A[(size_t)row * HID + lane]);
    float a1 = bf2f(A[(size_t)row * HID + 64 + lane]);
    float c0 = a0 * Ws[lane * 3 + 0] + a1 * Ws[(lane + 64) * 3 + 0];
    float c1 = a0 * Ws[lane * 3 + 1] + a1 * Ws[(lane + 64) * 3 + 1];
    float c2 = a0 * Ws[lane * 3 + 2] + a1 * Ws[(lane + 64) * 3 + 2];
#pragma unroll
    for (int o = 32; o > 0; o >>= 1) {
        c0 += __shfl_down(c0, o);
        c1 += __shfl_down(c1, o);
        c2 += __shfl_down(c2, o);
    }
    if (lane == 0) {
        c0 += bs[0]; c1 += bs[1]; c2 += bs[2];
        if (bf) {
            unsigned short* out = (unsigned short*)outv;
            out[(size_t)row * 3 + 0] = f2bf(c0);
            out[(size_t)row * 3 + 1] = f2bf(c1);
            out[(size_t)row * 3 + 2] = f2bf(c2);
        } else {
            float* out = (float*)outv;
            out[(size_t)row * 3 + 0] = c0;
            out[(size_t)row * 3 + 1] = c1;
            out[(size_t)row * 3 + 2] = c2;
        }
    }
}

extern "C" void kernel_launch(void* const* d_in, const int* in_sizes, int n_in,
                              void* d_out, int out_size, void* d_ws, size_t ws_size,
                              hipStream_t stream) {
    const void* x = nullptr; const int* ei = nullptr;
    const void* W1 = nullptr; const void* W5 = nullptr; const void* b5 = nullptr;
    const void* Wmid[3] = {nullptr, nullptr, nullptr};
    const void* bvec[4] = {nullptr, nullptr, nullptr, nullptr};
    int nw = 0, nb = 0;
    for (int i = 0; i < n_in; i++) {
        int s = in_sizes[i];
        if      (s == 50000000) x = d_in[i];
        else if (s == 3200000)  ei = (const int*)d_in[i];
        else if (s == 64000)    W1 = d_in[i];
        else if (s == 16384)  { if (nw < 3) Wmid[nw++] = d_in[i]; }
        else if (s == 384)      W5 = d_in[i];
        else if (s == 128)    { if (nb < 4) bvec[nb++] = d_in[i]; }
        else if (s == 3)        b5 = d_in[i];
    }
    if (!x || !ei || !W1 || !W5 || !b5 || nw < 3 || nb < 4) return;

    char* p = (char*)d_ws;
    auto alloc = [&](size_t bytes) { char* q = p; p += (bytes + 255) & ~(size_t)255; return (void*)q; };
    int*   flags = (int*)alloc(256);
    float* dis   = (float*)alloc((size_t)NNP * 4);
    int*   cnt   = (int*)alloc((size_t)NN * 4);
    int*   off   = (int*)alloc((size_t)(NN + 1) * 4);
    int*   bsum  = (int*)alloc(128 * 4);
    int*   rank  = (int*)alloc((size_t)NE * 4);
    int*   csr   = (int*)alloc((size_t)NE * 4);
    unsigned short* Wt1 = (unsigned short*)alloc((size_t)128 * 512 * 2);
    unsigned short* Wt2 = (unsigned short*)alloc((size_t)128 * 128 * 2);
    unsigned short* Wt3 = (unsigned short*)alloc((size_t)128 * 128 * 2);
    unsigned short* Wt4 = (unsigned short*)alloc((size_t)128 * 128 * 2);
    unsigned short* T   = (unsigned short*)alloc((size_t)NNP * HID * 2);
    unsigned short* H   = (unsigned short*)alloc((size_t)NNP * HID * 2);

    // graph build + weight transposes
    GCNLarge_20761871909627_kernel<<<(NN + 255) / 256, 256, 0, stream>>>(cnt, NN);
    detect_kernel<<<1, 64, 0, stream>>>(ei, (const unsigned int*)x, flags);
    wt_kernel<<<256, 256, 0, stream>>>(W1, flags, Wt1, FIN, 512, 128 * 512);
    wt_kernel<<<64, 256, 0, stream>>>(Wmid[0], flags, Wt2, HID, 128, 128 * 128);
    wt_kernel<<<64, 256, 0, stream>>>(Wmid[1], flags, Wt3, HID, 128, 128 * 128);
    wt_kernel<<<64, 256, 0, stream>>>(Wmid[2], flags, Wt4, HID, 128, 128 * 128);
    count_kernel<<<(NE + 1023) / 1024, 256, 0, stream>>>(ei, flags, cnt, rank);
    dis_kernel<<<(NNP + 255) / 256, 256, 0, stream>>>(cnt, dis);
    scan1_kernel<<<98, 1024, 0, stream>>>(cnt, off, bsum);
    scan2_kernel<<<1, 64, 0, stream>>>(bsum, 98);
    scan3_kernel<<<98, 1024, 0, stream>>>(off, bsum);
    place_kernel<<<(NE + 1023) / 1024, 256, 0, stream>>>(ei, flags, off, rank, csr);

    // layer 1
    gemm1g_kernel<<<NNP / 64, 256, 0, stream>>>(x, Wt1, dis, flags, T);
    aggb_kernel<<<NN / 4, 256, 0, stream>>>(T, off, csr, dis, bvec[0], flags, H, 1, 0);
    // layers 2-4 (T/H ping-pong), 391 blocks x 4 tiles x 64 rows = NNP
    gemmWr_kernel<<<NNP / 256, 256, 0, stream>>>(H, Wt2, dis, T);
    aggb_kernel<<<NN / 4, 256, 0, stream>>>(T, off, csr, dis, bvec[1], flags, H, 1, 0);
    gemmWr_kernel<<<NNP / 256, 256, 0, stream>>>(H, Wt3, dis, T);
    aggb_kernel<<<NN / 4, 256, 0, stream>>>(T, off, csr, dis, bvec[2], flags, H, 1, 0);
    gemmWr_kernel<<<NNP / 256, 256, 0, stream>>>(H, Wt4, dis, T);
    aggb_kernel<<<NN / 4, 256, 0, stream>>>(T, off, csr, dis, bvec[3], flags, H, 1, 0);
    // layer 5: aggregate first (linearity), then small GEMM
    aggb_kernel<<<NN / 4, 256, 0, stream>>>(H, off, csr, dis, nullptr, flags, T, 0, 1);
    gemm5_kernel<<<NN / 4, 256, 0, stream>>>(T, W5, b5, flags, d_out);
}

// Round 11
// 873.339 us; speedup vs baseline: 1.3118x; 1.3118x over previous
//
#include <hip/hip_runtime.h>
#include <hip/hip_bf16.h>

#define NN 100000
#define NNP 100096   // padded rows: multiple of 256
#define NE 1600000
#define FIN 500
#define HID 128

typedef __attribute__((ext_vector_type(8))) short short8;   // 8 bf16 = 4 VGPRs (MFMA A/B frag)
typedef __attribute__((ext_vector_type(4))) float f32x4;    // MFMA C/D frag

__device__ __forceinline__ float bf2f(unsigned short u) {
    return __uint_as_float(((unsigned int)u) << 16);
}
__device__ __forceinline__ unsigned short f2bf(float f) {
    __hip_bfloat16 h = __float2bfloat16(f);
    return *(unsigned short*)&h;
}
__device__ __forceinline__ float lo16(unsigned int v) { return __uint_as_float(v << 16); }
__device__ __forceinline__ float hi16(unsigned int v) { return __uint_as_float(v & 0xffff0000u); }

// direct global->LDS 16B: no result VGPRs, so all staging loads stay in flight.
__device__ __forceinline__ void gload_lds16(const void* g, void* l) {
    __builtin_amdgcn_global_load_lds(
        (const __attribute__((address_space(1))) unsigned int*)g,
        (__attribute__((address_space(3))) unsigned int*)l, 16, 0, 0);
}

// ---------- template-named kernel (serves as cnt zeroing) ----------

__global__ __launch_bounds__(256) void GCNLarge_20761871909627_kernel(int* __restrict__ buf, int n) {
    int i = blockIdx.x * 256 + threadIdx.x;
    if (i < n) buf[i] = 0;
}

// ---------- runtime layout detection (wave-parallel) ----------

__global__ void detect_kernel(const int* __restrict__ ei, const unsigned int* __restrict__ xw,
                              int* __restrict__ flags) {
    int lane = threadIdx.x & 63;
    int any = 0;
    for (int k = lane; k < 128; k += 64) any |= ei[2 * k + 1];
    int hits = 0;
    for (int k = lane; k < 256; k += 64) {
        unsigned e = (xw[k] >> 7) & 0xFF;
        hits += (e >= 100 && e <= 140) ? 1 : 0;
    }
#pragma unroll
    for (int o = 32; o > 0; o >>= 1) {
        any |= __shfl_down(any, o);
        hits += __shfl_down(hits, o);
    }
    if (lane == 0) {
        flags[0] = (any == 0) ? 1 : 0;
        flags[1] = (hits >= 128) ? 1 : 0;
    }
}

__device__ __forceinline__ int edge_src(const int* ei, int e, int m) {
    return m ? ei[2 * (size_t)e] : ei[e];
}
__device__ __forceinline__ int edge_dst(const int* ei, int e, int m) {
    return m ? ei[2 * (size_t)NE + 2 * (size_t)e] : ei[(size_t)NE + e];
}

// ---------- degree / CSR build ----------
// count's atomic return IS the edge's rank within its dst -> store rank[e]; place is
// atomic-free: csr[off[d]+rank[e]] = s. (round-6 fix, confirmed -73us)

__global__ __launch_bounds__(256) void count_kernel(const int* __restrict__ ei,
                                                    const int* __restrict__ flags,
                                                    int* __restrict__ cnt,
                                                    int* __restrict__ rank) {
    int m = flags[0];
    int base = blockIdx.x * 1024 + threadIdx.x;
#pragma unroll
    for (int i = 0; i < 4; i++) {
        int e = base + i * 256;
        if (e < NE) {
            int d = edge_dst(ei, e, m);
            if ((unsigned)d < NN) rank[e] = atomicAdd(&cnt[d], 1);
        }
    }
}

__global__ __launch_bounds__(256) void dis_kernel(const int* __restrict__ cnt,
                                                  float* __restrict__ dis) {
    int i = blockIdx.x * 256 + threadIdx.x;
    if (i < NNP) {
        int c = (i < NN) ? cnt[i] : 0;
        if (c < 0) c = 0;
        dis[i] = rsqrtf((float)(c + 1));
    }
}

__global__ __launch_bounds__(1024) void scan1_kernel(const int* __restrict__ cnt,
                                                     int* __restrict__ off,
                                                     int* __restrict__ bsum) {
    __shared__ int s[1024];
    int i = blockIdx.x * 1024 + threadIdx.x;
    int v = (i < NN) ? cnt[i] : 0;
    s[threadIdx.x] = v;
    __syncthreads();
    for (int d = 1; d < 1024; d <<= 1) {
        int tv = (threadIdx.x >= d) ? s[threadIdx.x - d] : 0;
        __syncthreads();
        s[threadIdx.x] += tv;
        __syncthreads();
    }
    if (i < NN) off[i] = s[threadIdx.x] - v;
    if (threadIdx.x == 1023) bsum[blockIdx.x] = s[1023];
}

__global__ void scan2_kernel(int* __restrict__ bsum, int nb) {
    if (threadIdx.x == 0 && blockIdx.x == 0) {
        int acc = 0;
        for (int b = 0; b < nb; b++) { int v = bsum[b]; bsum[b] = acc; acc += v; }
    }
}

__global__ __launch_bounds__(1024) void scan3_kernel(int* __restrict__ off,
                                                     const int* __restrict__ bsum) {
    int i = blockIdx.x * 1024 + threadIdx.x;
    if (i < NN) off[i] = off[i] + bsum[blockIdx.x];
    if (i == 0) off[NN] = NE;
}

// atomic-free placement: slot = off[d] + rank[e] (unique by construction)
__global__ __launch_bounds__(256) void place_kernel(const int* __restrict__ ei,
                                                    const int* __restrict__ flags,
                                                    const int* __restrict__ off,
                                                    const int* __restrict__ rank,
                                                    int* __restrict__ csr) {
    int m = flags[0];
    int base = blockIdx.x * 1024 + threadIdx.x;
#pragma unroll
    for (int i = 0; i < 4; i++) {
        int e = base + i * 256;
        if (e < NE) {
            int s = edge_src(ei, e, m);
            int d = edge_dst(ei, e, m);
            if ((unsigned)s < NN && (unsigned)d < NN) {
                int slot = off[d] + rank[e];
                if ((unsigned)slot < NE) csr[slot] = s;
            }
        }
    }
}

// ---------- W -> W^T (bf16) in global: Wt[n][k] = W[k][n], zero-padded to Kpad ----------

__global__ __launch_bounds__(256) void wt_kernel(const void* __restrict__ W,
                                                 const int* __restrict__ flags,
                                                 unsigned short* __restrict__ Wt,
                                                 int K, int Kpad, int total) {
    int idx = blockIdx.x * 256 + threadIdx.x;
    if (idx >= total) return;
    int n = idx / Kpad, k = idx - n * Kpad;
    unsigned short v = 0;
    if (k < K) {
        if (flags[1]) v = ((const unsigned short*)W)[(size_t)k * HID + n];
        else          v = f2bf(((const float*)W)[(size_t)k * HID + n]);
    }
    Wt[idx] = v;
}

// ---------- layers 2-4: barrier-free register GEMM ----------

__global__ __launch_bounds__(256) void gemmWr_kernel(const unsigned short* __restrict__ A,
                                                     const unsigned short* __restrict__ Wt,
                                                     const float* __restrict__ dis,
                                                     unsigned short* __restrict__ out) {
    int tid = threadIdx.x;
    int w = tid >> 6, lane = tid & 63;
    int m = lane & 15, quad = lane >> 4;
    int mbase = (w >> 1) * 32, nbase = (w & 1) * 64;
    short8 b[4][4];
#pragma unroll
    for (int nt = 0; nt < 4; nt++)
#pragma unroll
        for (int kq = 0; kq < 4; kq++)
            b[nt][kq] = *(const short8*)(Wt + (size_t)(nbase + nt * 16 + m) * HID + kq * 32 + quad * 8);
    int t0 = blockIdx.x * 4;
    short8 aP[4][2], aQ[4][2];
    auto loadA = [&](int t, short8 a[4][2]) {
        const unsigned short* p0 = A + (size_t)(t * 64 + mbase + m) * HID + quad * 8;
        const unsigned short* p1 = p0 + (size_t)16 * HID;
#pragma unroll
        for (int kq = 0; kq < 4; kq++) {
            a[kq][0] = *(const short8*)(p0 + kq * 32);
            a[kq][1] = *(const short8*)(p1 + kq * 32);
        }
    };
    loadA(t0, aP);
#pragma unroll
    for (int tt = 0; tt < 4; tt++) {
        if (tt < 3) loadA(t0 + tt + 1, (tt & 1) ? aP : aQ);
        short8 (*ac)[2] = (tt & 1) ? aQ : aP;
        f32x4 acc[2][4] = {};
#pragma unroll
        for (int kq = 0; kq < 4; kq++)
#pragma unroll
            for (int nt = 0; nt < 4; nt++) {
                acc[0][nt] = __builtin_amdgcn_mfma_f32_16x16x32_bf16(ac[kq][0], b[nt][kq], acc[0][nt], 0, 0, 0);
                acc[1][nt] = __builtin_amdgcn_mfma_f32_16x16x32_bf16(ac[kq][1], b[nt][kq], acc[1][nt], 0, 0, 0);
            }
        int r0 = (t0 + tt) * 64;
#pragma unroll
        for (int mt = 0; mt < 2; mt++) {
            int rb = r0 + mbase + mt * 16 + quad * 4;
#pragma unroll
            for (int reg = 0; reg < 4; reg++) {
                float d = dis[rb + reg];
#pragma unroll
                for (int nt = 0; nt < 4; nt++)
                    out[(size_t)(rb + reg) * HID + nbase + nt * 16 + m] = f2bf(acc[mt][nt][reg] * d);
            }
        }
    }
}

// ---------- layer 1: x [NN,500] @ Wt1[128][512], global_load_lds staging ----------

__global__ __launch_bounds__(256) void gemm1g_kernel(const void* __restrict__ Av,
                                                     const unsigned short* __restrict__ Wt1,
                                                     const float* __restrict__ dis,
                                                     const int* __restrict__ flags,
                                                     unsigned short* __restrict__ out) {
    __shared__ __align__(16) char lds[65536];
    float* AsF         = (float*)lds;                      // fp32 path: A slice [64][128] f32, 32KB
    unsigned short* Bs = (unsigned short*)(lds + 32768);   // B slice [128][128] bf16, 32KB
    unsigned short* As = (unsigned short*)lds;             // bf16 path: A slice [64][128] bf16, 16KB
    int tid = threadIdx.x;
    int bf = flags[1];
    int w = tid >> 6, lane = tid & 63;
    int m = lane & 15, quad = lane >> 4;
    int mbase = (w >> 1) * 32, nbase = (w & 1) * 64;
    int r0 = blockIdx.x * 64;
    f32x4 acc[2][4] = {};
    if (!bf) {
        // ---------------- fp32-x path (bench path) ----------------
#pragma unroll 1
        for (int kc = 0; kc < 4; kc++) {
            // B: 2048 16B slots; slot s=(n,cs) holds global chunk cs^(n&7)
#pragma unroll
            for (int i = 0; i < 8; i++) {
                int base = (i * 4 + w) * 64;
                int s = base + lane;
                int n = s >> 4, cs = s & 15;
                int csrc = cs ^ (n & 7);
                gload_lds16((const char*)Wt1 + (size_t)n * 1024 + kc * 256 + csrc * 16,
                            (char*)Bs + (size_t)base * 16);
            }
            // A: 2048 16B slots (fp32); slot s=(r,cs) holds global chunk cs^(r&7)
#pragma unroll
            for (int i = 0; i < 8; i++) {
                int base = (i * 4 + w) * 64;
                int s = base + lane;
                int r = s >> 5, cs = s & 31;
                int csrc = cs ^ (r & 7);
                int grow = r0 + r; int gr = (grow < NN) ? grow : NN - 1;
                int rb = kc * 512 + csrc * 16;          // byte offset within 2000B row
                size_t gb = (size_t)gr * 2000 + rb;
                if (rb + 16 > 2000) gb = 0;             // clamp OOB tail (x B-pad-zero)
                gload_lds16((const char*)Av + gb, (char*)lds + (size_t)base * 16);
            }
            __syncthreads();   // one vmcnt drain for all 16 loads/thread
#pragma unroll
            for (int kq = 0; kq < 4; kq++) {
                int g = kq * 4 + quad;
                int ra = mbase + m, rb2 = mbase + 16 + m;
                int fa = ra & 7, fb = rb2 & 7;
                float4 x0 = *(const float4*)(AsF + ra  * 128 + (((2 * g)     ^ fa) * 4));
                float4 x1 = *(const float4*)(AsF + ra  * 128 + (((2 * g + 1) ^ fa) * 4));
                float4 y0 = *(const float4*)(AsF + rb2 * 128 + (((2 * g)     ^ fb) * 4));
                float4 y1 = *(const float4*)(AsF + rb2 * 128 + (((2 * g + 1) ^ fb) * 4));
                short8 a0 = short8{(short)f2bf(x0.x), (short)f2bf(x0.y), (short)f2bf(x0.z), (short)f2bf(x0.w),
                                   (short)f2bf(x1.x), (short)f2bf(x1.y), (short)f2bf(x1.z), (short)f2bf(x1.w)};
                short8 a1 = short8{(short)f2bf(y0.x), (short)f2bf(y0.y), (short)f2bf(y0.z), (short)f2bf(y0.w),
                                   (short)f2bf(y1.x), (short)f2bf(y1.y), (short)f2bf(y1.z), (short)f2bf(y1.w)};
#pragma unroll
                for (int nt = 0; nt < 4; nt++) {
                    int n = nbase + nt * 16 + m;
                    short8 b = *(const short8*)(Bs + (size_t)n * 128 + ((g ^ (n & 7)) * 8));
                    acc[0][nt] = __builtin_amdgcn_mfma_f32_16x16x32_bf16(a0, b, acc[0][nt], 0, 0, 0);
                    acc[1][nt] = __builtin_amdgcn_mfma_f32_16x16x32_bf16(a1, b, acc[1][nt], 0, 0, 0);
                }
            }
            __syncthreads();   // protect slices from next kc staging
        }
    } else {
        // ---------------- bf16-x path (round-2 verified reg staging) ----------------
        int srow = tid >> 5;
        int scol = (tid & 31) * 4;
        int schunk = scol >> 3;
        int shalf = (scol >> 2) & 1;
#pragma unroll 1
        for (int kc = 0; kc < 4; kc++) {
#pragma unroll
            for (int it = 0; it < 8; it++) {
                int chunk = it * 256 + tid;
                int n = chunk >> 4, c = chunk & 15;
                int sc = c ^ (n & 15);
                *(short8*)(&Bs[n * 128 + c * 8]) =
                    *(const short8*)(Wt1 + (size_t)n * 512 + kc * 128 + sc * 8);
            }
#pragma unroll
            for (int i = 0; i < 8; i++) {
                int row = i * 8 + srow;
                int grow = r0 + row;
                int gr = (grow < NN) ? grow : NN - 1;
                int gcol = kc * 128 + scol;
                ushort4 pk = make_ushort4(0, 0, 0, 0);
                if (gcol + 4 <= FIN)
                    pk = *(const ushort4*)((const unsigned short*)Av + (size_t)gr * FIN + gcol);
                int pos = schunk ^ (row & 15);
                *(ushort4*)(&As[row * 128 + pos * 8 + shalf * 4]) = pk;
            }
            __syncthreads();
#pragma unroll
            for (int kq = 0; kq < 4; kq++) {
                int g = kq * 4 + quad;
                int ar0 = mbase + m;
                int ar1 = mbase + 16 + m;
                short8 a0 = *(const short8*)(&As[ar0 * 128 + ((g ^ m) * 8)]);
                short8 a1 = *(const short8*)(&As[ar1 * 128 + ((g ^ m) * 8)]);
#pragma unroll
                for (int nt = 0; nt < 4; nt++) {
                    int n = nbase + nt * 16 + m;
                    short8 b = *(const short8*)(&Bs[n * 128 + ((g ^ (n & 15)) * 8)]);
                    acc[0][nt] = __builtin_amdgcn_mfma_f32_16x16x32_bf16(a0, b, acc[0][nt], 0, 0, 0);
                    acc[1][nt] = __builtin_amdgcn_mfma_f32_16x16x32_bf16(a1, b, acc[1][nt], 0, 0, 0);
                }
            }
            __syncthreads();
        }
    }
#pragma unroll
    for (int mt = 0; mt < 2; mt++) {
        int rb = r0 + mbase + mt * 16 + quad * 4;
#pragma unroll
        for (int reg = 0; reg < 4; reg++) {
            int row = rb + reg;
            if (row < NN) {
                float d = dis[row];
#pragma unroll
                for (int nt = 0; nt < 4; nt++)
                    out[(size_t)row * HID + nbase + nt * 16 + m] = f2bf(acc[mt][nt][reg] * d);
            }
        }
    }
}

// ---------- aggregation: quarter-wave uint4 gathers ----------
// Round-9 post-mortem: 16-wide scalar-dword batch REGRESSED (90->139us): VGPR=40 shows
// the compiler refused to materialize the batch and re-serialized (same failure mode as
// gemm1 rounds 0-2: reg-staged scattered loads are scheduling-capped). Fix the
// instruction economics instead: each 16-lane group loads one edge's full 256B row as
// uint4 (16B/lane) -> ONE VMEM instr serves 4 edges. 8-instr batch = 32 edges in
// flight (1 latency pair for deg<=32, 99.99% of Poisson(16) nodes) in 32 value-VGPRs.
// Masking by weight-FMA (invalid -> self row addr, weight 0), no value selects.
// Cross-group combine: shfl_xor(16,32); group 0 stores the packed row.

__global__ __launch_bounds__(256) void aggb_kernel(const unsigned short* __restrict__ tin,
                                                   const int* __restrict__ off,
                                                   const int* __restrict__ csr,
                                                   const float* __restrict__ dis,
                                                   const void* __restrict__ bias,
                                                   const int* __restrict__ flags,
                                                   unsigned short* __restrict__ hout,
                                                   int relu, int scale_src) {
    int node = blockIdx.x * 4 + (threadIdx.x >> 6);   // one wave per node
    int lane = threadIdx.x & 63;
    int g = lane >> 4;            // edge group (4 edges per batch-instr)
    int fl = lane & 15;           // feature slot: features fl*8 .. fl*8+7
    float di = dis[node];
    float acc[8] = {};
    // self-loop contribution: group 0 only (others would quadruple it after reduce)
    {
        uint4 v = *(const uint4*)(tin + (size_t)node * HID + fl * 8);
        float w = (g == 0) ? (scale_src ? di : 1.0f) : 0.0f;
        acc[0] += w * lo16(v.x); acc[1] += w * hi16(v.x);
        acc[2] += w * lo16(v.y); acc[3] += w * hi16(v.y);
        acc[4] += w * lo16(v.z); acc[5] += w * hi16(v.z);
        acc[6] += w * lo16(v.w); acc[7] += w * hi16(v.w);
    }
    int e0 = off[node], e1 = off[node + 1];
    if (e0 < 0) e0 = 0;
    if (e1 > NE) e1 = NE;
    for (int e = e0; e < e1; e += 32) {
        int s[8];
        float wv[8];
        uint4 v[8];
#pragma unroll
        for (int j = 0; j < 8; j++) {
            int ej = e + j * 4 + g;
            s[j] = (ej < e1) ? csr[ej] : node;     // clamped: safe row, weight 0
        }
#pragma unroll
        for (int j = 0; j < 8; j++)
            v[j] = *(const uint4*)(tin + (size_t)s[j] * HID + fl * 8);
#pragma unroll
        for (int j = 0; j < 8; j++) {
            int ej = e + j * 4 + g;
            wv[j] = (ej < e1) ? (scale_src ? dis[s[j]] : 1.0f) : 0.0f;
        }
#pragma unroll
        for (int j = 0; j < 8; j++) {
            float w = wv[j];
            acc[0] += w * lo16(v[j].x); acc[1] += w * hi16(v[j].x);
            acc[2] += w * lo16(v[j].y); acc[3] += w * hi16(v[j].y);
            acc[4] += w * lo16(v[j].z); acc[5] += w * hi16(v[j].z);
            acc[6] += w * lo16(v[j].w); acc[7] += w * hi16(v[j].w);
        }
    }
    // combine the 4 edge-groups: lanes {fl, fl+16, fl+32, fl+48} hold partials
#pragma unroll
    for (int k = 0; k < 8; k++) {
        acc[k] += __shfl_xor(acc[k], 16);
        acc[k] += __shfl_xor(acc[k], 32);
    }
    float o[8];
#pragma unroll
    for (int k = 0; k < 8; k++) o[k] = di * acc[k];
    if (bias) {
        if (flags[1]) {
            const unsigned short* bb = (const unsigned short*)bias;
#pragma unroll
            for (int k = 0; k < 8; k++) o[k] += bf2f(bb[fl * 8 + k]);
        } else {
            const float* bb = (const float*)bias;
#pragma unroll
            for (int k = 0; k < 8; k++) o[k] += bb[fl * 8 + k];
        }
    }
    if (relu) {
#pragma unroll
        for (int k = 0; k < 8; k++) o[k] = fmaxf(o[k], 0.0f);
    }
    if (g == 0) {
        uint4 pk;
        pk.x = ((unsigned int)f2bf(o[1]) << 16) | (unsigned int)f2bf(o[0]);
        pk.y = ((unsigned int)f2bf(o[3]) << 16) | (unsigned int)f2bf(o[2]);
        pk.z = ((unsigned int)f2bf(o[5]) << 16) | (unsigned int)f2bf(o[4]);
        pk.w = ((unsigned int)f2bf(o[7]) << 16) | (unsigned int)f2bf(o[6]);
        *(uint4*)(hout + (size_t)node * HID + fl * 8) = pk;
    }
}

// ---------- layer 5: bf16 [NN,128] @ W5 [128,3] + b5 -> out (dtype per flags[1]) ----------

__global__ __launch_bounds__(256) void gemm5_kernel(const unsigned short* __restrict__ A,
                                                    const void* __restrict__ W5v,
                                                    const void* __restrict__ b5v,
                                                    const int* __restrict__ flags,
                                                    void* __restrict__ outv) {
    __shared__ float Ws[384];
    __shared__ float bs[3];
    int tid = threadIdx.x;
    int bf = flags[1];
    for (int idx = tid; idx < 384; idx += 256)
        Ws[idx] = bf ? bf2f(((const unsigned short*)W5v)[idx]) : ((const float*)W5v)[idx];
    if (tid < 3)
        bs[tid] = bf ? bf2f(((const unsigned short*)b5v)[tid]) : ((const float*)b5v)[tid];
    __syncthreads();
    int lane = tid & 63;
    int row = blockIdx.x * 4 + (tid >> 6);
    float a0 = bf2f(A[(size_t)row * HID + lane]);
    float a1 = bf2f(A[(size_t)row * HID + 64 + lane]);
    float c0 = a0 * Ws[lane * 3 + 0] + a1 * Ws[(lane + 64) * 3 + 0];
    float c1 = a0 * Ws[lane * 3 + 1] + a1 * Ws[(lane + 64) * 3 + 1];
    float c2 = a0 * Ws[lane * 3 + 2] + a1 * Ws[(lane + 64) * 3 + 2];
#pragma unroll
    for (int o = 32; o > 0; o >>= 1) {
        c0 += __shfl_down(c0, o);
        c1 += __shfl_down(c1, o);
        c2 += __shfl_down(c2, o);
    }
    if (lane == 0) {
        c0 += bs[0]; c1 += bs[1]; c2 += bs[2];
        if (bf) {
            unsigned short* out = (unsigned short*)outv;
            out[(size_t)row * 3 + 0] = f2bf(c0);
            out[(size_t)row * 3 + 1] = f2bf(c1);
            out[(size_t)row * 3 + 2] = f2bf(c2);
        } else {
            float* out = (float*)outv;
            out[(size_t)row * 3 + 0] = c0;
            out[(size_t)row * 3 + 1] = c1;
            out[(size_t)row * 3 + 2] = c2;
        }
    }
}

extern "C" void kernel_launch(void* const* d_in, const int* in_sizes, int n_in,
                              void* d_out, int out_size, void* d_ws, size_t ws_size,
                              hipStream_t stream) {
    const void* x = nullptr; const int* ei = nullptr;
    const void* W1 = nullptr; const void* W5 = nullptr; const void* b5 = nullptr;
    const void* Wmid[3] = {nullptr, nullptr, nullptr};
    const void* bvec[4] = {nullptr, nullptr, nullptr, nullptr};
    int nw = 0, nb = 0;
    for (int i = 0; i < n_in; i++) {
        int s = in_sizes[i];
        if      (s == 50000000) x = d_in[i];
        else if (s == 3200000)  ei = (const int*)d_in[i];
        else if (s == 64000)    W1 = d_in[i];
        else if (s == 16384)  { if (nw < 3) Wmid[nw++] = d_in[i]; }
        else if (s == 384)      W5 = d_in[i];
        else if (s == 128)    { if (nb < 4) bvec[nb++] = d_in[i]; }
        else if (s == 3)        b5 = d_in[i];
    }
    if (!x || !ei || !W1 || !W5 || !b5 || nw < 3 || nb < 4) return;

    char* p = (char*)d_ws;
    auto alloc = [&](size_t bytes) { char* q = p; p += (bytes + 255) & ~(size_t)255; return (void*)q; };
    int*   flags = (int*)alloc(256);
    float* dis   = (float*)alloc((size_t)NNP * 4);
    int*   cnt   = (int*)alloc((size_t)NN * 4);
    int*   off   = (int*)alloc((size_t)(NN + 1) * 4);
    int*   bsum  = (int*)alloc(128 * 4);
    int*   rank  = (int*)alloc((size_t)NE * 4);
    int*   csr   = (int*)alloc((size_t)NE * 4);
    unsigned short* Wt1 = (unsigned short*)alloc((size_t)128 * 512 * 2);
    unsigned short* Wt2 = (unsigned short*)alloc((size_t)128 * 128 * 2);
    unsigned short* Wt3 = (unsigned short*)alloc((size_t)128 * 128 * 2);
    unsigned short* Wt4 = (unsigned short*)alloc((size_t)128 * 128 * 2);
    unsigned short* T   = (unsigned short*)alloc((size_t)NNP * HID * 2);
    unsigned short* H   = (unsigned short*)alloc((size_t)NNP * HID * 2);

    // graph build + weight transposes
    GCNLarge_20761871909627_kernel<<<(NN + 255) / 256, 256, 0, stream>>>(cnt, NN);
    detect_kernel<<<1, 64, 0, stream>>>(ei, (const unsigned int*)x, flags);
    wt_kernel<<<256, 256, 0, stream>>>(W1, flags, Wt1, FIN, 512, 128 * 512);
    wt_kernel<<<64, 256, 0, stream>>>(Wmid[0], flags, Wt2, HID, 128, 128 * 128);
    wt_kernel<<<64, 256, 0, stream>>>(Wmid[1], flags, Wt3, HID, 128, 128 * 128);
    wt_kernel<<<64, 256, 0, stream>>>(Wmid[2], flags, Wt4, HID, 128, 128 * 128);
    count_kernel<<<(NE + 1023) / 1024, 256, 0, stream>>>(ei, flags, cnt, rank);
    dis_kernel<<<(NNP + 255) / 256, 256, 0, stream>>>(cnt, dis);
    scan1_kernel<<<98, 1024, 0, stream>>>(cnt, off, bsum);
    scan2_kernel<<<1, 64, 0, stream>>>(bsum, 98);
    scan3_kernel<<<98, 1024, 0, stream>>>(off, bsum);
    place_kernel<<<(NE + 1023) / 1024, 256, 0, stream>>>(ei, flags, off, rank, csr);

    // layer 1
    gemm1g_kernel<<<NNP / 64, 256, 0, stream>>>(x, Wt1, dis, flags, T);
    aggb_kernel<<<NN / 4, 256, 0, stream>>>(T, off, csr, dis, bvec[0], flags, H, 1, 0);
    // layers 2-4 (T/H ping-pong), 391 blocks x 4 tiles x 64 rows = NNP
    gemmWr_kernel<<<NNP / 256, 256, 0, stream>>>(H, Wt2, dis, T);
    aggb_kernel<<<NN / 4, 256, 0, stream>>>(T, off, csr, dis, bvec[1], flags, H, 1, 0);
    gemmWr_kernel<<<NNP / 256, 256, 0, stream>>>(H, Wt3, dis, T);
    aggb_kernel<<<NN / 4, 256, 0, stream>>>(T, off, csr, dis, bvec[2], flags, H, 1, 0);
    gemmWr_kernel<<<NNP / 256, 256, 0, stream>>>(H, Wt4, dis, T);
    aggb_kernel<<<NN / 4, 256, 0, stream>>>(T, off, csr, dis, bvec[3], flags, H, 1, 0);
    // layer 5: aggregate first (linearity), then small GEMM
    aggb_kernel<<<NN / 4, 256, 0, stream>>>(H, off, csr, dis, nullptr, flags, T, 0, 1);
    gemm5_kernel<<<NN / 4, 256, 0, stream>>>(T, W5, b5, flags, d_out);
}

// Round 13
// 863.300 us; speedup vs baseline: 1.3271x; 1.0116x over previous
//
#include <hip/hip_runtime.h>
#include <hip/hip_bf16.h>

#define NN 100000
#define NNP 100096   // padded rows: multiple of 256
#define NE 1600000
#define FIN 500
#define HID 128

typedef __attribute__((ext_vector_type(8))) short short8;   // 8 bf16 = 4 VGPRs (MFMA A/B frag)
typedef __attribute__((ext_vector_type(4))) float f32x4;    // MFMA C/D frag

__device__ __forceinline__ float bf2f(unsigned short u) {
    return __uint_as_float(((unsigned int)u) << 16);
}
__device__ __forceinline__ unsigned short f2bf(float f) {
    __hip_bfloat16 h = __float2bfloat16(f);
    return *(unsigned short*)&h;
}
__device__ __forceinline__ float lo16(unsigned int v) { return __uint_as_float(v << 16); }
__device__ __forceinline__ float hi16(unsigned int v) { return __uint_as_float(v & 0xffff0000u); }

// direct global->LDS 16B: no result VGPRs, so all staging loads stay in flight.
// LDS dest is wave-uniform base (HW adds lane*16); per-lane global source carries
// the swizzle (both-sides-or-neither, rule 21).
__device__ __forceinline__ void gload_lds16(const void* g, void* l) {
    __builtin_amdgcn_global_load_lds(
        (const __attribute__((address_space(1))) unsigned int*)g,
        (__attribute__((address_space(3))) unsigned int*)l, 16, 0, 0);
}

// ---------- template-named kernel (serves as cnt zeroing) ----------

__global__ __launch_bounds__(256) void GCNLarge_20761871909627_kernel(int* __restrict__ buf, int n) {
    int i = blockIdx.x * 256 + threadIdx.x;
    if (i < n) buf[i] = 0;
}

// ---------- runtime layout detection (wave-parallel) ----------

__global__ void detect_kernel(const int* __restrict__ ei, const unsigned int* __restrict__ xw,
                              int* __restrict__ flags) {
    int lane = threadIdx.x & 63;
    int any = 0;
    for (int k = lane; k < 128; k += 64) any |= ei[2 * k + 1];
    int hits = 0;
    for (int k = lane; k < 256; k += 64) {
        unsigned e = (xw[k] >> 7) & 0xFF;
        hits += (e >= 100 && e <= 140) ? 1 : 0;
    }
#pragma unroll
    for (int o = 32; o > 0; o >>= 1) {
        any |= __shfl_down(any, o);
        hits += __shfl_down(hits, o);
    }
    if (lane == 0) {
        flags[0] = (any == 0) ? 1 : 0;
        flags[1] = (hits >= 128) ? 1 : 0;
    }
}

__device__ __forceinline__ int edge_src(const int* ei, int e, int m) {
    return m ? ei[2 * (size_t)e] : ei[e];
}
__device__ __forceinline__ int edge_dst(const int* ei, int e, int m) {
    return m ? ei[2 * (size_t)NE + 2 * (size_t)e] : ei[(size_t)NE + e];
}

// ---------- degree / CSR build ----------
// count's atomic return IS the edge's rank within its dst -> store rank[e]; place is
// atomic-free: csr[off[d]+rank[e]] = s. (round-6 fix, confirmed -73us)

__global__ __launch_bounds__(256) void count_kernel(const int* __restrict__ ei,
                                                    const int* __restrict__ flags,
                                                    int* __restrict__ cnt,
                                                    int* __restrict__ rank) {
    int m = flags[0];
    int base = blockIdx.x * 1024 + threadIdx.x;
#pragma unroll
    for (int i = 0; i < 4; i++) {
        int e = base + i * 256;
        if (e < NE) {
            int d = edge_dst(ei, e, m);
            if ((unsigned)d < NN) rank[e] = atomicAdd(&cnt[d], 1);
        }
    }
}

__global__ __launch_bounds__(256) void dis_kernel(const int* __restrict__ cnt,
                                                  float* __restrict__ dis) {
    int i = blockIdx.x * 256 + threadIdx.x;
    if (i < NNP) {
        int c = (i < NN) ? cnt[i] : 0;
        if (c < 0) c = 0;
        dis[i] = rsqrtf((float)(c + 1));
    }
}

__global__ __launch_bounds__(1024) void scan1_kernel(const int* __restrict__ cnt,
                                                     int* __restrict__ off,
                                                     int* __restrict__ bsum) {
    __shared__ int s[1024];
    int i = blockIdx.x * 1024 + threadIdx.x;
    int v = (i < NN) ? cnt[i] : 0;
    s[threadIdx.x] = v;
    __syncthreads();
    for (int d = 1; d < 1024; d <<= 1) {
        int tv = (threadIdx.x >= d) ? s[threadIdx.x - d] : 0;
        __syncthreads();
        s[threadIdx.x] += tv;
        __syncthreads();
    }
    if (i < NN) off[i] = s[threadIdx.x] - v;
    if (threadIdx.x == 1023) bsum[blockIdx.x] = s[1023];
}

__global__ void scan2_kernel(int* __restrict__ bsum, int nb) {
    if (threadIdx.x == 0 && blockIdx.x == 0) {
        int acc = 0;
        for (int b = 0; b < nb; b++) { int v = bsum[b]; bsum[b] = acc; acc += v; }
    }
}

__global__ __launch_bounds__(1024) void scan3_kernel(int* __restrict__ off,
                                                     const int* __restrict__ bsum) {
    int i = blockIdx.x * 1024 + threadIdx.x;
    if (i < NN) off[i] = off[i] + bsum[blockIdx.x];
    if (i == 0) off[NN] = NE;
}

// atomic-free placement: slot = off[d] + rank[e] (unique by construction)
__global__ __launch_bounds__(256) void place_kernel(const int* __restrict__ ei,
                                                    const int* __restrict__ flags,
                                                    const int* __restrict__ off,
                                                    const int* __restrict__ rank,
                                                    int* __restrict__ csr) {
    int m = flags[0];
    int base = blockIdx.x * 1024 + threadIdx.x;
#pragma unroll
    for (int i = 0; i < 4; i++) {
        int e = base + i * 256;
        if (e < NE) {
            int s = edge_src(ei, e, m);
            int d = edge_dst(ei, e, m);
            if ((unsigned)s < NN && (unsigned)d < NN) {
                int slot = off[d] + rank[e];
                if ((unsigned)slot < NE) csr[slot] = s;
            }
        }
    }
}

// ---------- W -> W^T (bf16) in global: Wt[n][k] = W[k][n], zero-padded to Kpad ----------

__global__ __launch_bounds__(256) void wt_kernel(const void* __restrict__ W,
                                                 const int* __restrict__ flags,
                                                 unsigned short* __restrict__ Wt,
                                                 int K, int Kpad, int total) {
    int idx = blockIdx.x * 256 + threadIdx.x;
    if (idx >= total) return;
    int n = idx / Kpad, k = idx - n * Kpad;
    unsigned short v = 0;
    if (k < K) {
        if (flags[1]) v = ((const unsigned short*)W)[(size_t)k * HID + n];
        else          v = f2bf(((const float*)W)[(size_t)k * HID + n]);
    }
    Wt[idx] = v;
}

// ---------- layers 2-4: gload_lds-staged GEMM (round-11 rewrite) ----------
// Old gemmWr's A-loads were the rounds-0-2 scatter class: per VMEM instr 16 rows x 64B
// segments at 256B stride, reg-staged, MLP-capped (~1.3 TB/s effective). Rewrite with
// gemm1g's VERIFIED bf16 staging: A[64][128] (16KB) + B[128][128] (32KB) via
// global_load_lds (zero result VGPRs, all 12 loads/thread in flight, one vmcnt drain),
// involution swizzle: source chunk c^(row&15), frag read chunk g^m / g^(n&15)
// (2-way bank aliasing = free). 48KB LDS -> 3 blocks/CU.

__global__ __launch_bounds__(256) void gemmWs_kernel(const unsigned short* __restrict__ A,
                                                     const unsigned short* __restrict__ Wt,
                                                     const float* __restrict__ dis,
                                                     unsigned short* __restrict__ out) {
    __shared__ __align__(16) unsigned short As[64 * 128];    // 16 KB
    __shared__ __align__(16) unsigned short Bs[128 * 128];   // 32 KB
    int tid = threadIdx.x;
    int w = tid >> 6, lane = tid & 63;
    int m = lane & 15, quad = lane >> 4;
    int mbase = (w >> 1) * 32, nbase = (w & 1) * 64;
    int r0 = blockIdx.x * 64;
    // stage B: 2048 16B chunks, 8/thread; slot (n,c) holds source chunk c^(n&15)
#pragma unroll
    for (int i = 0; i < 8; i++) {
        int cb = i * 256 + w * 64;           // wave-uniform chunk base
        int chunk = cb + lane;
        int n = chunk >> 4, c = chunk & 15;
        int sc = c ^ (n & 15);
        gload_lds16((const char*)Wt + (size_t)n * 256 + sc * 16,
                    (char*)Bs + (size_t)cb * 16);
    }
    // stage A: 1024 16B chunks, 4/thread; slot (row,c) holds source chunk c^(row&15)
#pragma unroll
    for (int i = 0; i < 4; i++) {
        int cb = i * 256 + w * 64;
        int chunk = cb + lane;
        int row = chunk >> 4, c = chunk & 15;
        int sc = c ^ (row & 15);
        gload_lds16((const char*)A + (size_t)(r0 + row) * 256 + sc * 16,
                    (char*)As + (size_t)cb * 16);
    }
    __syncthreads();   // one vmcnt drain for all 12 loads/thread
    f32x4 acc[2][4] = {};
#pragma unroll
    for (int kq = 0; kq < 4; kq++) {
        int g = kq * 4 + quad;
        int ar0 = mbase + m, ar1 = mbase + 16 + m;
        short8 a0 = *(const short8*)(&As[ar0 * 128 + ((g ^ m) * 8)]);
        short8 a1 = *(const short8*)(&As[ar1 * 128 + ((g ^ m) * 8)]);
#pragma unroll
        for (int nt = 0; nt < 4; nt++) {
            int n = nbase + nt * 16 + m;
            short8 b = *(const short8*)(&Bs[n * 128 + ((g ^ (n & 15)) * 8)]);
            acc[0][nt] = __builtin_amdgcn_mfma_f32_16x16x32_bf16(a0, b, acc[0][nt], 0, 0, 0);
            acc[1][nt] = __builtin_amdgcn_mfma_f32_16x16x32_bf16(a1, b, acc[1][nt], 0, 0, 0);
        }
    }
#pragma unroll
    for (int mt = 0; mt < 2; mt++) {
        int rb = r0 + mbase + mt * 16 + quad * 4;
#pragma unroll
        for (int reg = 0; reg < 4; reg++) {
            float d = dis[rb + reg];
#pragma unroll
            for (int nt = 0; nt < 4; nt++)
                out[(size_t)(rb + reg) * HID + nbase + nt * 16 + m] = f2bf(acc[mt][nt][reg] * d);
        }
    }
}

// ---------- layer 1: x [NN,500] @ Wt1[128][512], global_load_lds staging ----------

__global__ __launch_bounds__(256) void gemm1g_kernel(const void* __restrict__ Av,
                                                     const unsigned short* __restrict__ Wt1,
                                                     const float* __restrict__ dis,
                                                     const int* __restrict__ flags,
                                                     unsigned short* __restrict__ out) {
    __shared__ __align__(16) char lds[65536];
    float* AsF         = (float*)lds;                      // fp32 path: A slice [64][128] f32, 32KB
    unsigned short* Bs = (unsigned short*)(lds + 32768);   // B slice [128][128] bf16, 32KB
    unsigned short* As = (unsigned short*)lds;             // bf16 path: A slice [64][128] bf16, 16KB
    int tid = threadIdx.x;
    int bf = flags[1];
    int w = tid >> 6, lane = tid & 63;
    int m = lane & 15, quad = lane >> 4;
    int mbase = (w >> 1) * 32, nbase = (w & 1) * 64;
    int r0 = blockIdx.x * 64;
    f32x4 acc[2][4] = {};
    if (!bf) {
        // ---------------- fp32-x path (bench path) ----------------
#pragma unroll 1
        for (int kc = 0; kc < 4; kc++) {
            // B: 2048 16B slots; slot s=(n,cs) holds global chunk cs^(n&7)
#pragma unroll
            for (int i = 0; i < 8; i++) {
                int base = (i * 4 + w) * 64;
                int s = base + lane;
                int n = s >> 4, cs = s & 15;
                int csrc = cs ^ (n & 7);
                gload_lds16((const char*)Wt1 + (size_t)n * 1024 + kc * 256 + csrc * 16,
                            (char*)Bs + (size_t)base * 16);
            }
            // A: 2048 16B slots (fp32); slot s=(r,cs) holds global chunk cs^(r&7)
#pragma unroll
            for (int i = 0; i < 8; i++) {
                int base = (i * 4 + w) * 64;
                int s = base + lane;
                int r = s >> 5, cs = s & 31;
                int csrc = cs ^ (r & 7);
                int grow = r0 + r; int gr = (grow < NN) ? grow : NN - 1;
                int rb = kc * 512 + csrc * 16;          // byte offset within 2000B row
                size_t gb = (size_t)gr * 2000 + rb;
                if (rb + 16 > 2000) gb = 0;             // clamp OOB tail (x B-pad-zero)
                gload_lds16((const char*)Av + gb, (char*)lds + (size_t)base * 16);
            }
            __syncthreads();   // one vmcnt drain for all 16 loads/thread
#pragma unroll
            for (int kq = 0; kq < 4; kq++) {
                int g = kq * 4 + quad;
                int ra = mbase + m, rb2 = mbase + 16 + m;
                int fa = ra & 7, fb = rb2 & 7;
                float4 x0 = *(const float4*)(AsF + ra  * 128 + (((2 * g)     ^ fa) * 4));
                float4 x1 = *(const float4*)(AsF + ra  * 128 + (((2 * g + 1) ^ fa) * 4));
                float4 y0 = *(const float4*)(AsF + rb2 * 128 + (((2 * g)     ^ fb) * 4));
                float4 y1 = *(const float4*)(AsF + rb2 * 128 + (((2 * g + 1) ^ fb) * 4));
                short8 a0 = short8{(short)f2bf(x0.x), (short)f2bf(x0.y), (short)f2bf(x0.z), (short)f2bf(x0.w),
                                   (short)f2bf(x1.x), (short)f2bf(x1.y), (short)f2bf(x1.z), (short)f2bf(x1.w)};
                short8 a1 = short8{(short)f2bf(y0.x), (short)f2bf(y0.y), (short)f2bf(y0.z), (short)f2bf(y0.w),
                                   (short)f2bf(y1.x), (short)f2bf(y1.y), (short)f2bf(y1.z), (short)f2bf(y1.w)};
#pragma unroll
                for (int nt = 0; nt < 4; nt++) {
                    int n = nbase + nt * 16 + m;
                    short8 b = *(const short8*)(Bs + (size_t)n * 128 + ((g ^ (n & 7)) * 8));
                    acc[0][nt] = __builtin_amdgcn_mfma_f32_16x16x32_bf16(a0, b, acc[0][nt], 0, 0, 0);
                    acc[1][nt] = __builtin_amdgcn_mfma_f32_16x16x32_bf16(a1, b, acc[1][nt], 0, 0, 0);
                }
            }
            __syncthreads();   // protect slices from next kc staging
        }
    } else {
        // ---------------- bf16-x path (round-2 verified reg staging) ----------------
        int srow = tid >> 5;
        int scol = (tid & 31) * 4;
        int schunk = scol >> 3;
        int shalf = (scol >> 2) & 1;
#pragma unroll 1
        for (int kc = 0; kc < 4; kc++) {
#pragma unroll
            for (int it = 0; it < 8; it++) {
                int chunk = it * 256 + tid;
                int n = chunk >> 4, c = chunk & 15;
                int sc = c ^ (n & 15);
                *(short8*)(&Bs[n * 128 + c * 8]) =
                    *(const short8*)(Wt1 + (size_t)n * 512 + kc * 128 + sc * 8);
            }
#pragma unroll
            for (int i = 0; i < 8; i++) {
                int row = i * 8 + srow;
                int grow = r0 + row;
                int gr = (grow < NN) ? grow : NN - 1;
                int gcol = kc * 128 + scol;
                ushort4 pk = make_ushort4(0, 0, 0, 0);
                if (gcol + 4 <= FIN)
                    pk = *(const ushort4*)((const unsigned short*)Av + (size_t)gr * FIN + gcol);
                int pos = schunk ^ (row & 15);
                *(ushort4*)(&As[row * 128 + pos * 8 + shalf * 4]) = pk;
            }
            __syncthreads();
#pragma unroll
            for (int kq = 0; kq < 4; kq++) {
                int g = kq * 4 + quad;
                int ar0 = mbase + m;
                int ar1 = mbase + 16 + m;
                short8 a0 = *(const short8*)(&As[ar0 * 128 + ((g ^ m) * 8)]);
                short8 a1 = *(const short8*)(&As[ar1 * 128 + ((g ^ m) * 8)]);
#pragma unroll
                for (int nt = 0; nt < 4; nt++) {
                    int n = nbase + nt * 16 + m;
                    short8 b = *(const short8*)(&Bs[n * 128 + ((g ^ (n & 15)) * 8)]);
                    acc[0][nt] = __builtin_amdgcn_mfma_f32_16x16x32_bf16(a0, b, acc[0][nt], 0, 0, 0);
                    acc[1][nt] = __builtin_amdgcn_mfma_f32_16x16x32_bf16(a1, b, acc[1][nt], 0, 0, 0);
                }
            }
            __syncthreads();
        }
    }
#pragma unroll
    for (int mt = 0; mt < 2; mt++) {
        int rb = r0 + mbase + mt * 16 + quad * 4;
#pragma unroll
        for (int reg = 0; reg < 4; reg++) {
            int row = rb + reg;
            if (row < NN) {
                float d = dis[row];
#pragma unroll
                for (int nt = 0; nt < 4; nt++)
                    out[(size_t)row * HID + nbase + nt * 16 + m] = f2bf(acc[mt][nt][reg] * d);
            }
        }
    }
}

// ---------- aggregation: quarter-wave uint4 gathers ----------
// Round-11 verdict: ~90us/pass, equal to the old serial 8/4/1 structure despite 4x
// fewer gather instructions and full MLP -> random-row gather SERVICE RATE bound
// (~190MB L2-miss traffic/pass at ~2.1 TB/s; traffic structural: every XCD's dsts
// reference ~all sources, so 8 XCDs x 25.6MB cold-fill is irreducible). At floor.

__global__ __launch_bounds__(256) void aggb_kernel(const unsigned short* __restrict__ tin,
                                                   const int* __restrict__ off,
                                                   const int* __restrict__ csr,
                                                   const float* __restrict__ dis,
                                                   const void* __restrict__ bias,
                                                   const int* __restrict__ flags,
                                                   unsigned short* __restrict__ hout,
                                                   int relu, int scale_src) {
    int node = blockIdx.x * 4 + (threadIdx.x >> 6);   // one wave per node
    int lane = threadIdx.x & 63;
    int g = lane >> 4;            // edge group (4 edges per batch-instr)
    int fl = lane & 15;           // feature slot: features fl*8 .. fl*8+7
    float di = dis[node];
    float acc[8] = {};
    // self-loop contribution: group 0 only (others would quadruple it after reduce)
    {
        uint4 v = *(const uint4*)(tin + (size_t)node * HID + fl * 8);
        float w = (g == 0) ? (scale_src ? di : 1.0f) : 0.0f;
        acc[0] += w * lo16(v.x); acc[1] += w * hi16(v.x);
        acc[2] += w * lo16(v.y); acc[3] += w * hi16(v.y);
        acc[4] += w * lo16(v.z); acc[5] += w * hi16(v.z);
        acc[6] += w * lo16(v.w); acc[7] += w * hi16(v.w);
    }
    int e0 = off[node], e1 = off[node + 1];
    if (e0 < 0) e0 = 0;
    if (e1 > NE) e1 = NE;
    for (int e = e0; e < e1; e += 32) {
        int s[8];
        float wv[8];
        uint4 v[8];
#pragma unroll
        for (int j = 0; j < 8; j++) {
            int ej = e + j * 4 + g;
            s[j] = (ej < e1) ? csr[ej] : node;     // clamped: safe row, weight 0
        }
#pragma unroll
        for (int j = 0; j < 8; j++)
            v[j] = *(const uint4*)(tin + (size_t)s[j] * HID + fl * 8);
#pragma unroll
        for (int j = 0; j < 8; j++) {
            int ej = e + j * 4 + g;
            wv[j] = (ej < e1) ? (scale_src ? dis[s[j]] : 1.0f) : 0.0f;
        }
#pragma unroll
        for (int j = 0; j < 8; j++) {
            float w = wv[j];
            acc[0] += w * lo16(v[j].x); acc[1] += w * hi16(v[j].x);
            acc[2] += w * lo16(v[j].y); acc[3] += w * hi16(v[j].y);
            acc[4] += w * lo16(v[j].z); acc[5] += w * hi16(v[j].z);
            acc[6] += w * lo16(v[j].w); acc[7] += w * hi16(v[j].w);
        }
    }
    // combine the 4 edge-groups: lanes {fl, fl+16, fl+32, fl+48} hold partials
#pragma unroll
    for (int k = 0; k < 8; k++) {
        acc[k] += __shfl_xor(acc[k], 16);
        acc[k] += __shfl_xor(acc[k], 32);
    }
    float o[8];
#pragma unroll
    for (int k = 0; k < 8; k++) o[k] = di * acc[k];
    if (bias) {
        if (flags[1]) {
            const unsigned short* bb = (const unsigned short*)bias;
#pragma unroll
            for (int k = 0; k < 8; k++) o[k] += bf2f(bb[fl * 8 + k]);
        } else {
            const float* bb = (const float*)bias;
#pragma unroll
            for (int k = 0; k < 8; k++) o[k] += bb[fl * 8 + k];
        }
    }
    if (relu) {
#pragma unroll
        for (int k = 0; k < 8; k++) o[k] = fmaxf(o[k], 0.0f);
    }
    if (g == 0) {
        uint4 pk;
        pk.x = ((unsigned int)f2bf(o[1]) << 16) | (unsigned int)f2bf(o[0]);
        pk.y = ((unsigned int)f2bf(o[3]) << 16) | (unsigned int)f2bf(o[2]);
        pk.z = ((unsigned int)f2bf(o[5]) << 16) | (unsigned int)f2bf(o[4]);
        pk.w = ((unsigned int)f2bf(o[7]) << 16) | (unsigned int)f2bf(o[6]);
        *(uint4*)(hout + (size_t)node * HID + fl * 8) = pk;
    }
}

// ---------- layer 5: bf16 [NN,128] @ W5 [128,3] + b5 -> out (dtype per flags[1]) ----------

__global__ __launch_bounds__(256) void gemm5_kernel(const unsigned short* __restrict__ A,
                                                    const void* __restrict__ W5v,
                                                    const void* __restrict__ b5v,
                                                    const int* __restrict__ flags,
                                                    void* __restrict__ outv) {
    __shared__ float Ws[384];
    __shared__ float bs[3];
    int tid = threadIdx.x;
    int bf = flags[1];
    for (int idx = tid; idx < 384; idx += 256)
        Ws[idx] = bf ? bf2f(((const unsigned short*)W5v)[idx]) : ((const float*)W5v)[idx];
    if (tid < 3)
        bs[tid] = bf ? bf2f(((const unsigned short*)b5v)[tid]) : ((const float*)b5v)[tid];
    __syncthreads();
    int lane = tid & 63;
    int row = blockIdx.x * 4 + (tid >> 6);
    float a0 = bf2f(A[(size_t)row * HID + lane]);
    float a1 = bf2f(A[(size_t)row * HID + 64 + lane]);
    float c0 = a0 * Ws[lane * 3 + 0] + a1 * Ws[(lane + 64) * 3 + 0];
    float c1 = a0 * Ws[lane * 3 + 1] + a1 * Ws[(lane + 64) * 3 + 1];
    float c2 = a0 * Ws[lane * 3 + 2] + a1 * Ws[(lane + 64) * 3 + 2];
#pragma unroll
    for (int o = 32; o > 0; o >>= 1) {
        c0 += __shfl_down(c0, o);
        c1 += __shfl_down(c1, o);
        c2 += __shfl_down(c2, o);
    }
    if (lane == 0) {
        c0 += bs[0]; c1 += bs[1]; c2 += bs[2];
        if (bf) {
            unsigned short* out = (unsigned short*)outv;
            out[(size_t)row * 3 + 0] = f2bf(c0);
            out[(size_t)row * 3 + 1] = f2bf(c1);
            out[(size_t)row * 3 + 2] = f2bf(c2);
        } else {
            float* out = (float*)outv;
            out[(size_t)row * 3 + 0] = c0;
            out[(size_t)row * 3 + 1] = c1;
            out[(size_t)row * 3 + 2] = c2;
        }
    }
}

extern "C" void kernel_launch(void* const* d_in, const int* in_sizes, int n_in,
                              void* d_out, int out_size, void* d_ws, size_t ws_size,
                              hipStream_t stream) {
    const void* x = nullptr; const int* ei = nullptr;
    const void* W1 = nullptr; const void* W5 = nullptr; const void* b5 = nullptr;
    const void* Wmid[3] = {nullptr, nullptr, nullptr};
    const void* bvec[4] = {nullptr, nullptr, nullptr, nullptr};
    int nw = 0, nb = 0;
    for (int i = 0; i < n_in; i++) {
        int s = in_sizes[i];
        if      (s == 50000000) x = d_in[i];
        else if (s == 3200000)  ei = (const int*)d_in[i];
        else if (s == 64000)    W1 = d_in[i];
        else if (s == 16384)  { if (nw < 3) Wmid[nw++] = d_in[i]; }
        else if (s == 384)      W5 = d_in[i];
        else if (s == 128)    { if (nb < 4) bvec[nb++] = d_in[i]; }
        else if (s == 3)        b5 = d_in[i];
    }
    if (!x || !ei || !W1 || !W5 || !b5 || nw < 3 || nb < 4) return;

    char* p = (char*)d_ws;
    auto alloc = [&](size_t bytes) { char* q = p; p += (bytes + 255) & ~(size_t)255; return (void*)q; };
    int*   flags = (int*)alloc(256);
    float* dis   = (float*)alloc((size_t)NNP * 4);
    int*   cnt   = (int*)alloc((size_t)NN * 4);
    int*   off   = (int*)alloc((size_t)(NN + 1) * 4);
    int*   bsum  = (int*)alloc(128 * 4);
    int*   rank  = (int*)alloc((size_t)NE * 4);
    int*   csr   = (int*)alloc((size_t)NE * 4);
    unsigned short* Wt1 = (unsigned short*)alloc((size_t)128 * 512 * 2);
    unsigned short* Wt2 = (unsigned short*)alloc((size_t)128 * 128 * 2);
    unsigned short* Wt3 = (unsigned short*)alloc((size_t)128 * 128 * 2);
    unsigned short* Wt4 = (unsigned short*)alloc((size_t)128 * 128 * 2);
    unsigned short* T   = (unsigned short*)alloc((size_t)NNP * HID * 2);
    unsigned short* H   = (unsigned short*)alloc((size_t)NNP * HID * 2);

    // graph build + weight transposes
    GCNLarge_20761871909627_kernel<<<(NN + 255) / 256, 256, 0, stream>>>(cnt, NN);
    detect_kernel<<<1, 64, 0, stream>>>(ei, (const unsigned int*)x, flags);
    wt_kernel<<<256, 256, 0, stream>>>(W1, flags, Wt1, FIN, 512, 128 * 512);
    wt_kernel<<<64, 256, 0, stream>>>(Wmid[0], flags, Wt2, HID, 128, 128 * 128);
    wt_kernel<<<64, 256, 0, stream>>>(Wmid[1], flags, Wt3, HID, 128, 128 * 128);
    wt_kernel<<<64, 256, 0, stream>>>(Wmid[2], flags, Wt4, HID, 128, 128 * 128);
    count_kernel<<<(NE + 1023) / 1024, 256, 0, stream>>>(ei, flags, cnt, rank);
    dis_kernel<<<(NNP + 255) / 256, 256, 0, stream>>>(cnt, dis);
    scan1_kernel<<<98, 1024, 0, stream>>>(cnt, off, bsum);
    scan2_kernel<<<1, 64, 0, stream>>>(bsum, 98);
    scan3_kernel<<<98, 1024, 0, stream>>>(off, bsum);
    place_kernel<<<(NE + 1023) / 1024, 256, 0, stream>>>(ei, flags, off, rank, csr);

    // layer 1
    gemm1g_kernel<<<NNP / 64, 256, 0, stream>>>(x, Wt1, dis, flags, T);
    aggb_kernel<<<NN / 4, 256, 0, stream>>>(T, off, csr, dis, bvec[0], flags, H, 1, 0);
    // layers 2-4 (T/H ping-pong), 1564 blocks x 64 rows = NNP
    gemmWs_kernel<<<NNP / 64, 256, 0, stream>>>(H, Wt2, dis, T);
    aggb_kernel<<<NN / 4, 256, 0, stream>>>(T, off, csr, dis, bvec[1], flags, H, 1, 0);
    gemmWs_kernel<<<NNP / 64, 256, 0, stream>>>(H, Wt3, dis, T);
    aggb_kernel<<<NN / 4, 256, 0, stream>>>(T, off, csr, dis, bvec[2], flags, H, 1, 0);
    gemmWs_kernel<<<NNP / 64, 256, 0, stream>>>(H, Wt4, dis, T);
    aggb_kernel<<<NN / 4, 256, 0, stream>>>(T, off, csr, dis, bvec[3], flags, H, 1, 0);
    // layer 5: aggregate first (linearity), then small GEMM
    aggb_kernel<<<NN / 4, 256, 0, stream>>>(H, off, csr, dis, nullptr, flags, T, 0, 1);
    gemm5_kernel<<<NN / 4, 256, 0, stream>>>(T, W5, b5, flags, d_out);
}